// Round 8
// baseline (246.975 us; speedup 1.0000x reference)
//
#include <hip/hip_runtime.h>
#include <hip/hip_bf16.h>

typedef __bf16 bf16;
typedef __attribute__((ext_vector_type(8))) __bf16 bf16x8;
typedef __attribute__((ext_vector_type(4))) __bf16 bf16x4v;
typedef __attribute__((ext_vector_type(4))) float f32x4;

#define B_  16
#define C_  256
#define HW_ 1024
#define PADR 1156              // 34*34 padded rows per z
#define ZSTR 295936            // 1156*256 elements per z in fTpad

__device__ __forceinline__ void gll16(const bf16* g, bf16* l) {
  __builtin_amdgcn_global_load_lds((const __attribute__((address_space(1))) void*)g,
                                   (__attribute__((address_space(3))) void*)l, 16, 0, 0);
}

// ---- fused rnorm + transpose into padded layout (borders zeroed here) + weight reorder.
// blocks [0,1024): rn[z][k] = 1/||f[z][:,k]||; fTpad[z][(h+1)*34+(w+1)][c] = bf16(f[z][c][h*32+w])
// blocks [1024,5632): Wr[t][c][d*256+cin] = w_t[c][cin][kh][kw]
__global__ void prep_fat(const float* __restrict__ f0, const float* __restrict__ f1,
                         const float* __restrict__ w0, const float* __restrict__ w1,
                         bf16* __restrict__ fTpad, float* __restrict__ rn,
                         bf16* __restrict__ Wr) {
  int tid = threadIdx.x;
  if (blockIdx.x >= 1024) {
    int i = (blockIdx.x - 1024) * 256 + tid;   // [0, 2*589824)
    int t = i / 589824, r2 = i % 589824;
    int c = r2 / 2304, r = r2 % 2304;
    int cin = r / 9, d = r % 9;
    Wr[(size_t)t * 589824 + c * 2304 + d * 256 + cin] = (bf16)(t ? w1 : w0)[r2];
    return;
  }
  __shared__ float sm[256][33];
  __shared__ float ps[8][32];
  int bx = blockIdx.x & 31, z = blockIdx.x >> 5;
  int t = z >> 4, b = z & 15;
  int k0 = bx * 32;                      // h = bx, k = k0 + w
  const float* fb = (t ? f1 : f0) + (size_t)b * C_ * HW_ + k0;
  int kk = tid & 31, cg = tid >> 5;
  float ssq = 0.f;
  #pragma unroll
  for (int i = 0; i < 32; ++i) {
    int c = cg + i * 8;
    float v = fb[(size_t)c * HW_ + kk];
    sm[c][kk] = v;
    ssq += v * v;
  }
  ps[cg][kk] = ssq;

  bf16x8 zv;
  #pragma unroll
  for (int e = 0; e < 8; ++e) zv[e] = (bf16)0.f;
  if (tid < 64) {
    int c = (tid & 31) * 8, side = tid >> 5;
    *(bf16x8*)(fTpad + ((size_t)z * PADR + (bx + 1) * 34 + side * 33) * C_ + c) = zv;
  }
  if (bx == 0 || bx == 31) {
    int prow = (bx == 0) ? 0 : 33;
    for (int q = tid; q < 34 * 32; q += 256) {
      int wcol = q >> 5, c = (q & 31) * 8;
      *(bf16x8*)(fTpad + ((size_t)z * PADR + prow * 34 + wcol) * C_ + c) = zv;
    }
  }

  __syncthreads();
  if (tid < 32) {
    float s = 0.f;
    #pragma unroll
    for (int r = 0; r < 8; ++r) s += ps[r][tid];
    rn[z * 1024 + k0 + tid] = 1.f / fmaxf(sqrtf(s), 1e-12f);
  }
  int wl = tid >> 3, c0 = (tid & 7) * 32;
  bf16* dst = fTpad + ((size_t)z * PADR + (bx + 1) * 34 + wl + 1) * C_ + c0;
  #pragma unroll
  for (int u = 0; u < 4; ++u) {
    bf16x8 vv;
    #pragma unroll
    for (int e = 0; e < 8; ++e) vv[e] = (bf16)sm[c0 + u * 8 + e][wl];
    *(bf16x8*)(dst + u * 8) = vv;
  }
}

// ---- grouped 3x3 fusion conv over BOTH tasks; writes M row (b,i) IN PLACE over aff0 row (b,i)
__global__ void fusion_conv2(const bf16* __restrict__ aff, const float* __restrict__ fw,
                             const float* __restrict__ fb, bf16* __restrict__ M) {
  __shared__ float sa[2][1024];
  int bi = blockIdx.x;           // b*1024 + i
  int i = bi & 1023, b = bi >> 10;
  int tid = threadIdx.x;
  #pragma unroll
  for (int t = 0; t < 2; ++t) {
    const bf16* arow = aff + (((size_t)t * 16 + b) * 1024 + i) * 1024;
    bf16x4v ch = ((const bf16x4v*)arow)[tid];
    sa[t][tid * 4 + 0] = (float)ch[0];
    sa[t][tid * 4 + 1] = (float)ch[1];
    sa[t][tid * 4 + 2] = (float)ch[2];
    sa[t][tid * 4 + 3] = (float)ch[3];
  }
  float wgt[2][9];
  #pragma unroll
  for (int t = 0; t < 2; ++t)
    #pragma unroll
    for (int q = 0; q < 9; ++q) wgt[t][q] = fw[i * 18 + t * 9 + q];
  float bias = fb[i];
  __syncthreads();
  #pragma unroll
  for (int s0 = 0; s0 < 4; ++s0) {
    int s = tid + s0 * 256;
    int h = s >> 5, w = s & 31;
    float acc = bias;
    #pragma unroll
    for (int kh = 0; kh < 3; ++kh) {
      int hh = h + kh - 1;
      if ((unsigned)hh < 32u) {
        #pragma unroll
        for (int kw = 0; kw < 3; ++kw) {
          int ww = w + kw - 1;
          if ((unsigned)ww < 32u) {
            acc += wgt[0][kh * 3 + kw] * sa[0][hh * 32 + ww];
            acc += wgt[1][kh * 3 + kw] * sa[1][hh * 32 + ww];
          }
        }
      }
    }
    M[((size_t)bi << 10) + s] = (bf16)acc;
  }
}

// ---------------- NT GEMM core: C[m,n] = sum_k A[m,k]*B[n,k], 128x128 tile, MFMA 16x16x32 ----
// All tiles staged via global_load_lds with XOR chunk swizzle p = c ^ (row & 7).
// Per-lane source base pointers hoisted out of the K-loop; per-iter offset is wave-uniform.
// MODE 1: aff SYRK on fTpad rows; z = t*16+b;  store bf16 C * rn[row] * rn[col].
// MODE 2: attend; z pair-major (t=z&1, b=z>>1): A=value[z], B=Mbuf[b];
//         store fp32 0.5*C + 0.5*feat at task-major offset.
// MODE 3: value conv; z pair-major: A=Wr[t], B=fTpad[t*16+b] shifted rows; +bias; C=value[z].
template<int MODE>
__device__ __forceinline__
void gemm_core(int bx, int by, int z, bf16* As, bf16* Bs,
               const bf16* __restrict__ A, long long sA,
               const bf16* __restrict__ Bm, long long sB, int K,
               bf16* __restrict__ Cb, long long sC,
               const float* __restrict__ x0, const float* __restrict__ x1,
               float* __restrict__ Co) {
  const int tt = (MODE == 1) ? (z >> 4) : (z & 1);
  const int bb = (MODE == 1) ? (z & 15) : (z >> 1);
  const int zold = tt * 16 + bb;
  const bf16* Ab = A + (size_t)(MODE == 3 ? tt : z) * sA;
  const bf16* Bb = Bm + (size_t)(MODE == 1 ? z : (MODE == 2 ? bb : zold)) * sB;
  const int m0 = by * 128, n0 = bx * 128;
  const int tid = threadIdx.x;
  const int lane = tid & 63, wave = tid >> 6;
  const int wm = (wave >> 1) * 64, wn = (wave & 1) * 64;
  const int fr = lane & 15, fq = lane >> 4;

  const bf16* srcA[4];
  const bf16* srcB[4];
  int ldsA[4], ldsB[4];
  #pragma unroll
  for (int s = 0; s < 4; ++s) {
    int q = (wave * 4 + s) * 64 + lane;
    int row = q >> 3, c = (q & 7) ^ (row & 7);
    ldsA[s] = ldsB[s] = __builtin_amdgcn_readfirstlane((wave * 4 + s) * 512);
    if (MODE == 1) {
      int j = m0 + row;
      srcA[s] = Ab + (size_t)(((j >> 5) + 1) * 34 + (j & 31) + 1) * C_ + c * 8;
    } else {
      srcA[s] = Ab + (size_t)(m0 + row) * K + c * 8;
    }
    int jb = n0 + row;
    if (MODE == 1 || MODE == 3) {
      srcB[s] = Bb + (size_t)(((jb >> 5) + 1) * 34 + (jb & 31) + 1) * C_ + c * 8;
    } else {
      srcB[s] = Bb + (size_t)jb * K + c * 8;
    }
  }
  int lA[2][4], lB[2][4];
  #pragma unroll
  for (int h = 0; h < 2; ++h) {
    #pragma unroll
    for (int i = 0; i < 4; ++i) {
      int rr = wm + i * 16 + fr;
      lA[h][i] = rr * 64 + (((h * 4) + fq) ^ (rr & 7)) * 8;
      int rc = wn + i * 16 + fr;
      lB[h][i] = rc * 64 + (((h * 4) + fq) ^ (rc & 7)) * 8;
    }
  }

  f32x4 acc[4][4];
  #pragma unroll
  for (int i = 0; i < 4; ++i)
    #pragma unroll
    for (int j = 0; j < 4; ++j) acc[i][j] = 0.f;

  for (int k0 = 0; k0 < K; k0 += 64) {
    int boff;
    if (MODE == 3) {
      int d = k0 >> 8;
      int kh = d / 3, kw = d % 3;
      boff = ((kh - 1) * 34 + (kw - 1)) * C_ + (k0 & 255);
    } else {
      boff = k0;
    }
    #pragma unroll
    for (int s = 0; s < 4; ++s) gll16(srcA[s] + k0, As + ldsA[s]);
    #pragma unroll
    for (int s = 0; s < 4; ++s) gll16(srcB[s] + boff, Bs + ldsB[s]);
    __syncthreads();
    #pragma unroll
    for (int h = 0; h < 2; ++h) {
      bf16x8 af[4], bfr[4];
      #pragma unroll
      for (int i = 0; i < 4; ++i) af[i] = *(const bf16x8*)(&As[lA[h][i]]);
      #pragma unroll
      for (int j = 0; j < 4; ++j) bfr[j] = *(const bf16x8*)(&Bs[lB[h][j]]);
      #pragma unroll
      for (int i = 0; i < 4; ++i)
        #pragma unroll
        for (int j = 0; j < 4; ++j)
          acc[i][j] = __builtin_amdgcn_mfma_f32_16x16x32_bf16(af[i], bfr[j], acc[i][j], 0, 0, 0);
    }
    __syncthreads();
  }

  // epilogue: D element (reg r, lane) -> row = quad*4 + r, col = lane&15  [m89/m91]
  #pragma unroll
  for (int i = 0; i < 4; ++i) {
    int rbase = m0 + wm + i * 16 + fq * 4;
    #pragma unroll
    for (int j = 0; j < 4; ++j) {
      int col = n0 + wn + j * 16 + fr;
      float cj = (MODE == 1) ? x0[(size_t)z * 1024 + col] : 0.f;
      #pragma unroll
      for (int r = 0; r < 4; ++r) {
        int row = rbase + r;
        float v = acc[i][j][r];
        if (MODE == 1) {
          Cb[(size_t)z * sC + (size_t)row * 1024 + col] =
              (bf16)(v * x0[(size_t)z * 1024 + row] * cj);
        } else if (MODE == 3) {
          const float* bias = tt ? x1 : x0;
          Cb[(size_t)z * sC + (size_t)row * 1024 + col] = (bf16)(v + bias[row]);
        } else {
          const float* fp = tt ? x1 : x0;
          Co[(size_t)zold * sC + (size_t)row * 1024 + col] =
              0.5f * v + 0.5f * fp[(size_t)bb * sC + (size_t)row * 1024 + col];
        }
      }
    }
  }
}

// ---- fat dispatch: blocks [0,2048) = aff SYRK (MODE 1); [2048,2560) = value conv (MODE 3).
// Independent work co-scheduled so value's low-block-count phase overlaps aff's MFMA.
__global__ __launch_bounds__(256, 4)
void gemm_fat(const bf16* __restrict__ fTpad, const float* __restrict__ rn,
              bf16* __restrict__ aff, const bf16* __restrict__ Wr,
              bf16* __restrict__ value, const float* __restrict__ b0,
              const float* __restrict__ b1) {
  __shared__ bf16 As[128 * 64];
  __shared__ bf16 Bs[128 * 64];
  int blk = blockIdx.x;
  if (blk < 2048) {
    gemm_core<1>(blk & 7, (blk >> 3) & 7, blk >> 6, As, Bs,
                 fTpad, ZSTR, fTpad, ZSTR, C_,
                 aff, (long long)HW_ * HW_, rn, rn, nullptr);
  } else {
    int q = blk - 2048;
    gemm_core<3>(q & 7, (q >> 3) & 1, q >> 4, As, Bs,
                 Wr, 589824LL, fTpad, ZSTR, 2304,
                 value, (long long)C_ * HW_, b0, b1, nullptr);
  }
}

__global__ __launch_bounds__(256, 4)
void gemm_attend(const bf16* __restrict__ value, const bf16* __restrict__ Mbuf,
                 const float* __restrict__ f0, const float* __restrict__ f1,
                 float* __restrict__ out) {
  __shared__ bf16 As[128 * 64];
  __shared__ bf16 Bs[128 * 64];
  gemm_core<2>(blockIdx.x, blockIdx.y, blockIdx.z, As, Bs,
               value, (long long)C_ * HW_, Mbuf, (long long)HW_ * HW_, 1024,
               nullptr, (long long)C_ * HW_, f0, f1, out);
}

extern "C" void kernel_launch(void* const* d_in, const int* in_sizes, int n_in,
                              void* d_out, int out_size, void* d_ws, size_t ws_size,
                              hipStream_t stream) {
  const float* f0 = (const float*)d_in[0];
  const float* f1 = (const float*)d_in[1];
  const float* w0 = (const float*)d_in[2];
  const float* b0 = (const float*)d_in[3];
  const float* w1 = (const float*)d_in[4];
  const float* b1 = (const float*)d_in[5];
  const float* fusion_w = (const float*)d_in[6];
  const float* fusion_b = (const float*)d_in[7];
  float* out = (float*)d_out;

  // workspace (~86.2 MB peak):
  //   aff [2 tasks] at 0..67.1M; Mbuf written IN PLACE over aff0 by fusion_conv2;
  //   value does NOT alias aff (both live during gemm_fat): value gets its own slab.
  char* ws = (char*)d_ws;
  bf16* aff   = (bf16*)ws;                       // 67,108,864  [2 tasks]
  bf16* Mbuf  = (bf16*)ws;                       // in-place over aff0
  bf16* fTpad = (bf16*)(ws + 67108864ull);       // 18,939,904
  bf16* Wr    = (bf16*)(ws + 86048768ull);       //  2,359,296
  bf16* value = (bf16*)(ws + 88408064ull);       // 16,777,216
  float* rn   = (float*)(ws + 105185280ull);     //    131,072

  prep_fat<<<5632, 256, 0, stream>>>(f0, f1, w0, w1, fTpad, rn, Wr);
  // fat dispatch: aff SYRK (2048 blocks) + value conv GEMM (512 blocks), independent
  gemm_fat<<<2560, 256, 0, stream>>>(fTpad, rn, aff, Wr, value, b0, b1);
  fusion_conv2<<<16384, 256, 0, stream>>>(aff, fusion_w, fusion_b, Mbuf);
  // out[t][b][c][j] = 0.5 * sum_k value[zp][c][k] * Mbuf[b][j][k] + 0.5 * f_t[b][c][j]
  gemm_attend<<<dim3(8, 2, 32), 256, 0, stream>>>(value, Mbuf, f0, f1, out);
}

// Round 9
// 233.197 us; speedup vs baseline: 1.0591x; 1.0591x over previous
//
#include <hip/hip_runtime.h>
#include <hip/hip_bf16.h>

typedef __bf16 bf16;
typedef __attribute__((ext_vector_type(8))) __bf16 bf16x8;
typedef __attribute__((ext_vector_type(4))) __bf16 bf16x4v;
typedef __attribute__((ext_vector_type(4))) float f32x4;

#define B_  16
#define C_  256
#define HW_ 1024
#define PADR 1156              // 34*34 padded rows per z
#define ZSTR 295936            // 1156*256 elements per z in fTpad
#define TP  133                // transpose-tile LDS pad (8-distinct-bank stride)

__device__ __forceinline__ void gll16(const bf16* g, bf16* l) {
  __builtin_amdgcn_global_load_lds((const __attribute__((address_space(1))) void*)g,
                                   (__attribute__((address_space(3))) void*)l, 16, 0, 0);
}

// ---- fused rnorm + transpose into padded layout (borders zeroed here) + weight reorder.
// blocks [0,1024): rn[z][k] = 1/||f[z][:,k]||; fTpad[z][(h+1)*34+(w+1)][c] = bf16(f[z][c][h*32+w])
// blocks [1024,5632): Wr[t][c][d*256+cin] = w_t[c][cin][kh][kw]
__global__ void prep_fat(const float* __restrict__ f0, const float* __restrict__ f1,
                         const float* __restrict__ w0, const float* __restrict__ w1,
                         bf16* __restrict__ fTpad, float* __restrict__ rn,
                         bf16* __restrict__ Wr) {
  int tid = threadIdx.x;
  if (blockIdx.x >= 1024) {
    int i = (blockIdx.x - 1024) * 256 + tid;   // [0, 2*589824)
    int t = i / 589824, r2 = i % 589824;
    int c = r2 / 2304, r = r2 % 2304;
    int cin = r / 9, d = r % 9;
    Wr[(size_t)t * 589824 + c * 2304 + d * 256 + cin] = (bf16)(t ? w1 : w0)[r2];
    return;
  }
  __shared__ float sm[256][33];
  __shared__ float ps[8][32];
  int bx = blockIdx.x & 31, z = blockIdx.x >> 5;
  int t = z >> 4, b = z & 15;
  int k0 = bx * 32;                      // h = bx, k = k0 + w
  const float* fb = (t ? f1 : f0) + (size_t)b * C_ * HW_ + k0;
  int kk = tid & 31, cg = tid >> 5;
  float ssq = 0.f;
  #pragma unroll
  for (int i = 0; i < 32; ++i) {
    int c = cg + i * 8;
    float v = fb[(size_t)c * HW_ + kk];
    sm[c][kk] = v;
    ssq += v * v;
  }
  ps[cg][kk] = ssq;

  bf16x8 zv;
  #pragma unroll
  for (int e = 0; e < 8; ++e) zv[e] = (bf16)0.f;
  if (tid < 64) {
    int c = (tid & 31) * 8, side = tid >> 5;
    *(bf16x8*)(fTpad + ((size_t)z * PADR + (bx + 1) * 34 + side * 33) * C_ + c) = zv;
  }
  if (bx == 0 || bx == 31) {
    int prow = (bx == 0) ? 0 : 33;
    for (int q = tid; q < 34 * 32; q += 256) {
      int wcol = q >> 5, c = (q & 31) * 8;
      *(bf16x8*)(fTpad + ((size_t)z * PADR + prow * 34 + wcol) * C_ + c) = zv;
    }
  }

  __syncthreads();
  if (tid < 32) {
    float s = 0.f;
    #pragma unroll
    for (int r = 0; r < 8; ++r) s += ps[r][tid];
    rn[z * 1024 + k0 + tid] = 1.f / fmaxf(sqrtf(s), 1e-12f);
  }
  int wl = tid >> 3, c0 = (tid & 7) * 32;
  bf16* dst = fTpad + ((size_t)z * PADR + (bx + 1) * 34 + wl + 1) * C_ + c0;
  #pragma unroll
  for (int u = 0; u < 4; ++u) {
    bf16x8 vv;
    #pragma unroll
    for (int e = 0; e < 8; ++e) vv[e] = (bf16)sm[c0 + u * 8 + e][wl];
    *(bf16x8*)(dst + u * 8) = vv;
  }
}

// ---- grouped 3x3 fusion conv over BOTH tasks; writes M row (b,i) IN PLACE over aff0 row (b,i)
__global__ void fusion_conv2(const bf16* __restrict__ aff, const float* __restrict__ fw,
                             const float* __restrict__ fb, bf16* __restrict__ M) {
  __shared__ float sa[2][1024];
  int bi = blockIdx.x;           // b*1024 + i
  int i = bi & 1023, b = bi >> 10;
  int tid = threadIdx.x;
  #pragma unroll
  for (int t = 0; t < 2; ++t) {
    const bf16* arow = aff + (((size_t)t * 16 + b) * 1024 + i) * 1024;
    bf16x4v ch = ((const bf16x4v*)arow)[tid];
    sa[t][tid * 4 + 0] = (float)ch[0];
    sa[t][tid * 4 + 1] = (float)ch[1];
    sa[t][tid * 4 + 2] = (float)ch[2];
    sa[t][tid * 4 + 3] = (float)ch[3];
  }
  float wgt[2][9];
  #pragma unroll
  for (int t = 0; t < 2; ++t)
    #pragma unroll
    for (int q = 0; q < 9; ++q) wgt[t][q] = fw[i * 18 + t * 9 + q];
  float bias = fb[i];
  __syncthreads();
  #pragma unroll
  for (int s0 = 0; s0 < 4; ++s0) {
    int s = tid + s0 * 256;
    int h = s >> 5, w = s & 31;
    float acc = bias;
    #pragma unroll
    for (int kh = 0; kh < 3; ++kh) {
      int hh = h + kh - 1;
      if ((unsigned)hh < 32u) {
        #pragma unroll
        for (int kw = 0; kw < 3; ++kw) {
          int ww = w + kw - 1;
          if ((unsigned)ww < 32u) {
            acc += wgt[0][kh * 3 + kw] * sa[0][hh * 32 + ww];
            acc += wgt[1][kh * 3 + kw] * sa[1][hh * 32 + ww];
          }
        }
      }
    }
    M[((size_t)bi << 10) + s] = (bf16)acc;
  }
}

// ---------------- NT GEMM core: C[m,n] = sum_k A[m,k]*B[n,k], 128x128 tile, MFMA 16x16x32 ----
// All tiles staged via global_load_lds with XOR chunk swizzle p = c ^ (row & 7).
// MODE 1: aff SYRK, upper-triangle tiles only (by<=bx); z = t*16+b;
//         store bf16 C * rn[row] * rn[col]; off-diagonal tiles also write the mirror
//         tile (bx,by) via LDS transpose (T = smem reuse, pad TP).
// MODE 2: attend; z pair-major (t=z&1, b=z>>1): A=value[z], B=Mbuf[b];
//         store fp32 0.5*C + 0.5*feat at task-major offset.
// MODE 3: value conv; z pair-major: A=Wr[t], B=fTpad[t*16+b] shifted rows; +bias; C=value[z].
template<int MODE>
__device__ __forceinline__
void gemm_core(int bx, int by, int z, bf16* As, bf16* Bs, bf16* T,
               const bf16* __restrict__ A, long long sA,
               const bf16* __restrict__ Bm, long long sB, int K,
               bf16* __restrict__ Cb, long long sC,
               const float* __restrict__ x0, const float* __restrict__ x1,
               float* __restrict__ Co) {
  const int tt = (MODE == 1) ? (z >> 4) : (z & 1);
  const int bb = (MODE == 1) ? (z & 15) : (z >> 1);
  const int zold = tt * 16 + bb;
  const bf16* Ab = A + (size_t)(MODE == 3 ? tt : z) * sA;
  const bf16* Bb = Bm + (size_t)(MODE == 1 ? z : (MODE == 2 ? bb : zold)) * sB;
  const int m0 = by * 128, n0 = bx * 128;
  const int tid = threadIdx.x;
  const int lane = tid & 63, wave = tid >> 6;
  const int wm = (wave >> 1) * 64, wn = (wave & 1) * 64;
  const int fr = lane & 15, fq = lane >> 4;

  const bf16* srcA[4];
  const bf16* srcB[4];
  int ldsA[4], ldsB[4];
  #pragma unroll
  for (int s = 0; s < 4; ++s) {
    int q = (wave * 4 + s) * 64 + lane;
    int row = q >> 3, c = (q & 7) ^ (row & 7);
    ldsA[s] = ldsB[s] = __builtin_amdgcn_readfirstlane((wave * 4 + s) * 512);
    if (MODE == 1) {
      int j = m0 + row;
      srcA[s] = Ab + (size_t)(((j >> 5) + 1) * 34 + (j & 31) + 1) * C_ + c * 8;
    } else {
      srcA[s] = Ab + (size_t)(m0 + row) * K + c * 8;
    }
    int jb = n0 + row;
    if (MODE == 1 || MODE == 3) {
      srcB[s] = Bb + (size_t)(((jb >> 5) + 1) * 34 + (jb & 31) + 1) * C_ + c * 8;
    } else {
      srcB[s] = Bb + (size_t)jb * K + c * 8;
    }
  }
  int lA[2][4], lB[2][4];
  #pragma unroll
  for (int h = 0; h < 2; ++h) {
    #pragma unroll
    for (int i = 0; i < 4; ++i) {
      int rr = wm + i * 16 + fr;
      lA[h][i] = rr * 64 + (((h * 4) + fq) ^ (rr & 7)) * 8;
      int rc = wn + i * 16 + fr;
      lB[h][i] = rc * 64 + (((h * 4) + fq) ^ (rc & 7)) * 8;
    }
  }

  f32x4 acc[4][4];
  #pragma unroll
  for (int i = 0; i < 4; ++i)
    #pragma unroll
    for (int j = 0; j < 4; ++j) acc[i][j] = 0.f;

  for (int k0 = 0; k0 < K; k0 += 64) {
    int boff;
    if (MODE == 3) {
      int d = k0 >> 8;
      int kh = d / 3, kw = d % 3;
      boff = ((kh - 1) * 34 + (kw - 1)) * C_ + (k0 & 255);
    } else {
      boff = k0;
    }
    #pragma unroll
    for (int s = 0; s < 4; ++s) gll16(srcA[s] + k0, As + ldsA[s]);
    #pragma unroll
    for (int s = 0; s < 4; ++s) gll16(srcB[s] + boff, Bs + ldsB[s]);
    __syncthreads();
    #pragma unroll
    for (int h = 0; h < 2; ++h) {
      bf16x8 af[4], bfr[4];
      #pragma unroll
      for (int i = 0; i < 4; ++i) af[i] = *(const bf16x8*)(&As[lA[h][i]]);
      #pragma unroll
      for (int j = 0; j < 4; ++j) bfr[j] = *(const bf16x8*)(&Bs[lB[h][j]]);
      #pragma unroll
      for (int i = 0; i < 4; ++i)
        #pragma unroll
        for (int j = 0; j < 4; ++j)
          acc[i][j] = __builtin_amdgcn_mfma_f32_16x16x32_bf16(af[i], bfr[j], acc[i][j], 0, 0, 0);
    }
    __syncthreads();
  }

  // epilogue: D element (reg r, lane) -> row = quad*4 + r, col = lane&15  [m89/m91]
  const bool mirror = (MODE == 1) && (bx != by);
  #pragma unroll
  for (int i = 0; i < 4; ++i) {
    int rbase = m0 + wm + i * 16 + fq * 4;
    #pragma unroll
    for (int j = 0; j < 4; ++j) {
      int col = n0 + wn + j * 16 + fr;
      float cj = (MODE == 1) ? x0[(size_t)z * 1024 + col] : 0.f;
      #pragma unroll
      for (int r = 0; r < 4; ++r) {
        int row = rbase + r;
        float v = acc[i][j][r];
        if (MODE == 1) {
          bf16 sv = (bf16)(v * x0[(size_t)z * 1024 + row] * cj);
          Cb[(size_t)z * sC + (size_t)row * 1024 + col] = sv;
          if (mirror) T[(row - m0) * TP + (col - n0)] = sv;
        } else if (MODE == 3) {
          const float* bias = tt ? x1 : x0;
          Cb[(size_t)z * sC + (size_t)row * 1024 + col] = (bf16)(v + bias[row]);
        } else {
          const float* fp = tt ? x1 : x0;
          Co[(size_t)zold * sC + (size_t)row * 1024 + col] =
              0.5f * v + 0.5f * fp[(size_t)bb * sC + (size_t)row * 1024 + col];
        }
      }
    }
  }
  if (mirror) {
    __syncthreads();
    // write transposed tile at (bx,by): out row = n0-local g, out col = m0-local c
    #pragma unroll
    for (int s = 0; s < 8; ++s) {
      int q2 = s * 256 + tid;            // 2048 16B chunks
      int g = q2 >> 4, c0 = (q2 & 15) << 3;
      bf16x8 vv;
      #pragma unroll
      for (int e = 0; e < 8; ++e) vv[e] = T[(c0 + e) * TP + g];
      *(bf16x8*)(Cb + (size_t)z * sC + (size_t)(n0 + g) * 1024 + m0 + c0) = vv;
    }
  }
}

__global__ __launch_bounds__(256, 4)
void gemm_aff(const bf16* __restrict__ fTpad, const float* __restrict__ rn,
              bf16* __restrict__ aff) {
  __shared__ bf16 smem[128 * TP];        // 17024 elems >= 2*8192 (As+Bs) ; T aliases base
  int q = blockIdx.x, by = 0, cnt = 8;
  while (q >= cnt) { q -= cnt; ++by; --cnt; }
  int bx = by + q;
  gemm_core<1>(bx, by, blockIdx.z, smem, smem + 8192, smem,
               fTpad, ZSTR, fTpad, ZSTR, C_,
               aff, (long long)HW_ * HW_, rn, rn, nullptr);
}

__global__ __launch_bounds__(256, 4)
void gemm_value(const bf16* __restrict__ Wr, const bf16* __restrict__ fTpad,
                bf16* __restrict__ value, const float* __restrict__ b0,
                const float* __restrict__ b1) {
  __shared__ bf16 smem[128 * 128];
  gemm_core<3>(blockIdx.x, blockIdx.y, blockIdx.z, smem, smem + 8192, smem,
               Wr, 589824LL, fTpad, ZSTR, 2304,
               value, (long long)C_ * HW_, b0, b1, nullptr);
}

__global__ __launch_bounds__(256, 4)
void gemm_attend(const bf16* __restrict__ value, const bf16* __restrict__ Mbuf,
                 const float* __restrict__ f0, const float* __restrict__ f1,
                 float* __restrict__ out) {
  __shared__ bf16 smem[128 * 128];
  gemm_core<2>(blockIdx.x, blockIdx.y, blockIdx.z, smem, smem + 8192, smem,
               value, (long long)C_ * HW_, Mbuf, (long long)HW_ * HW_, 1024,
               nullptr, (long long)C_ * HW_, f0, f1, out);
}

extern "C" void kernel_launch(void* const* d_in, const int* in_sizes, int n_in,
                              void* d_out, int out_size, void* d_ws, size_t ws_size,
                              hipStream_t stream) {
  const float* f0 = (const float*)d_in[0];
  const float* f1 = (const float*)d_in[1];
  const float* w0 = (const float*)d_in[2];
  const float* b0 = (const float*)d_in[3];
  const float* w1 = (const float*)d_in[4];
  const float* b1 = (const float*)d_in[5];
  const float* fusion_w = (const float*)d_in[6];
  const float* fusion_b = (const float*)d_in[7];
  float* out = (float*)d_out;

  // workspace (~105 MB peak):
  //   aff [2 tasks] at 0..67.1M; Mbuf written IN PLACE over aff0 by fusion_conv2;
  //   fTpad / Wr / value / rn above (value kept separate from aff).
  char* ws = (char*)d_ws;
  bf16* aff   = (bf16*)ws;                       // 67,108,864  [2 tasks]
  bf16* Mbuf  = (bf16*)ws;                       // in-place over aff0
  bf16* fTpad = (bf16*)(ws + 67108864ull);       // 18,939,904
  bf16* Wr    = (bf16*)(ws + 86048768ull);       //  2,359,296
  bf16* value = (bf16*)(ws + 88408064ull);       // 16,777,216
  float* rn   = (float*)(ws + 105185280ull);     //    131,072

  prep_fat<<<5632, 256, 0, stream>>>(f0, f1, w0, w1, fTpad, rn, Wr);
  // aff[z][i][j] = (sum_c fT[z][i][c] * fT[z][j][c]) * rn[z][i] * rn[z][j]  (SYRK, 36 tiles/z)
  gemm_aff<<<dim3(36, 1, 32), 256, 0, stream>>>(fTpad, rn, aff);
  // value[zp][c][j] = conv(f_t, w_t)[b][c][j] + bias_t[c]   (zp pair-major: t=zp&1, b=zp>>1)
  gemm_value<<<dim3(8, 2, 32), 256, 0, stream>>>(Wr, fTpad, value, b0, b1);
  fusion_conv2<<<16384, 256, 0, stream>>>(aff, fusion_w, fusion_b, Mbuf);
  // out[t][b][c][j] = 0.5 * sum_k value[zp][c][k] * Mbuf[b][j][k] + 0.5 * f_t[b][c][j]
  gemm_attend<<<dim3(8, 2, 32), 256, 0, stream>>>(value, Mbuf, f0, f1, out);
}